// Round 1
// baseline (14998.676 us; speedup 1.0000x reference)
//
#include <hip/hip_runtime.h>
#include <cstdint>
#include <cstddef>

namespace {
constexpr int Dh = 512;   // hidden / emb dim
constexpr int G3 = 1536;  // 3*Dh
constexpr int NB = 256;   // batch
constexpr int SL = 256;   // src len
constexpr int TL = 256;   // trg len
constexpr int NV = 512;   // vocab
}

__device__ __forceinline__ unsigned short f2bf(float f) {
  unsigned int u = __float_as_uint(f);
  u = (u + 0x7FFFu + ((u >> 16) & 1u)) >> 16;  // RNE, values are finite/small
  return (unsigned short)u;
}
__device__ __forceinline__ float bf2f(unsigned short s) {
  return __uint_as_float(((unsigned int)s) << 16);
}

// naive transpose: in[R][C] -> out[C][R] (tiny matrices, one-time cost)
__global__ void transpose_f32(const float* __restrict__ in, float* __restrict__ out,
                              int R, int C) {
  int i = blockIdx.x * 256 + threadIdx.x;
  if (i < R * C) {
    int r = i / C, c = i - r * C;
    out[(size_t)c * R + r] = in[i];
  }
}

// C[M,N] = A @ B + bias.  B is [K][N] row-major (pre-transposed weights).
// AMODE 0: A row ptr = Abase + idx[row]*K  (embedding gather, optional RELU)
// AMODE 1: A row ptr = Abase + ((row & 255)*NB + (row >> 8)) * K  (h_all[t*NB+b] for row=b*TL+t)
// 128x128 tile, BK=16, 256 threads, 8x8 micro-tile.
template <int AMODE, bool RELU, bool OUTBF16>
__global__ __launch_bounds__(256) void gemm128(
    const float* __restrict__ Abase, const int* __restrict__ idx,
    const float* __restrict__ Bm, const float* __restrict__ bias,
    void* __restrict__ Cout, int N, int K) {
  __shared__ float As[16][132];
  __shared__ float Bs[16][132];
  const int t = threadIdx.x;
  const int n0 = blockIdx.x * 128;
  const int m0 = blockIdx.y * 128;
  const int mt = t >> 4, nt = t & 15;

  // hoist the 8 A-row pointers (gather/transmap resolved once)
  const float* arow[8];
#pragma unroll
  for (int i = 0; i < 8; ++i) {
    int m = i * 16 + (t >> 4);
    int row = m0 + m;
    if (AMODE == 0)
      arow[i] = Abase + (size_t)idx[row] * K;
    else
      arow[i] = Abase + ((size_t)(row & (TL - 1)) * NB + (row >> 8)) * K;
  }
  const int kk_a = t & 15;

  float acc[8][8];
#pragma unroll
  for (int i = 0; i < 8; ++i)
#pragma unroll
    for (int j = 0; j < 8; ++j) acc[i][j] = 0.f;

  const int nn = t & 127, kb = t >> 7;
  for (int k0 = 0; k0 < K; k0 += 16) {
#pragma unroll
    for (int i = 0; i < 8; ++i) {
      float v = arow[i][k0 + kk_a];
      if (RELU) v = fmaxf(v, 0.f);
      As[kk_a][i * 16 + (t >> 4)] = v;
    }
#pragma unroll
    for (int i = 0; i < 8; ++i) {
      int kk = i * 2 + kb;
      Bs[kk][nn] = Bm[(size_t)(k0 + kk) * N + n0 + nn];
    }
    __syncthreads();
#pragma unroll
    for (int kk = 0; kk < 16; ++kk) {
      float a[8], b[8];
      *(float4*)&a[0] = *(const float4*)&As[kk][mt * 8];
      *(float4*)&a[4] = *(const float4*)&As[kk][mt * 8 + 4];
      *(float4*)&b[0] = *(const float4*)&Bs[kk][nt * 8];
      *(float4*)&b[4] = *(const float4*)&Bs[kk][nt * 8 + 4];
#pragma unroll
      for (int i = 0; i < 8; ++i)
#pragma unroll
        for (int j = 0; j < 8; ++j) acc[i][j] = fmaf(a[i], b[j], acc[i][j]);
    }
    __syncthreads();
  }

  const int col0 = n0 + nt * 8;
  float bv[8];
#pragma unroll
  for (int j = 0; j < 8; ++j) bv[j] = bias[col0 + j];
#pragma unroll
  for (int i = 0; i < 8; ++i) {
    size_t row = (size_t)m0 + mt * 8 + i;
    float v[8];
#pragma unroll
    for (int j = 0; j < 8; ++j) v[j] = acc[i][j] + bv[j];
    if (OUTBF16) {
      unsigned short* crow = (unsigned short*)Cout + row * N + col0;
      ushort4 p0, p1;
      p0.x = f2bf(v[0]); p0.y = f2bf(v[1]); p0.z = f2bf(v[2]); p0.w = f2bf(v[3]);
      p1.x = f2bf(v[4]); p1.y = f2bf(v[5]); p1.z = f2bf(v[6]); p1.w = f2bf(v[7]);
      *(ushort4*)crow = p0;
      *(ushort4*)(crow + 4) = p1;
    } else {
      float* crow = (float*)Cout + row * N + col0;
      float4 f0, f1;
      f0.x = v[0]; f0.y = v[1]; f0.z = v[2]; f0.w = v[3];
      f1.x = v[4]; f1.y = v[5]; f1.z = v[6]; f1.w = v[7];
      *(float4*)crow = f0;
      *(float4*)(crow + 4) = f1;
    }
  }
}

// One GRU time step, fused gh-GEMM + gates.
// grid (Dh/32, NB/16) = (16,16) -> 256 WGs; each WG owns a 16b x 32d output tile
// and computes all three gate columns (d, D+d, 2D+d) so no intra-step sync needed.
// WT = WhhT [512][1536]; gi = bf16 [NB*seq][1536] (already includes bih).
__global__ __launch_bounds__(256) void gru_step(
    const float* __restrict__ h_in, float* __restrict__ h_out,
    const float* __restrict__ WT, const unsigned short* __restrict__ gi,
    const float* __restrict__ bhh, int t, int seq) {
  __shared__ float Hs[32][18];
  __shared__ float Ws[32][104];  // 3 gates x 32 d per k-row, padded pitch
  const int tid = threadIdx.x;
  const int d0 = blockIdx.x * 32;
  const int b0 = blockIdx.y * 16;
  const int bb = tid >> 4;  // 0..15 batch row
  const int dg = tid & 15;  // 0..15 d-group (2 d each)
  float ar[2] = {0.f, 0.f}, az[2] = {0.f, 0.f}, an[2] = {0.f, 0.f};

  for (int k0 = 0; k0 < Dh; k0 += 32) {
#pragma unroll
    for (int i = 0; i < 2; ++i) {
      int e = i * 256 + tid;
      int kk = e & 31, r = e >> 5;
      Hs[kk][r] = h_in[(size_t)(b0 + r) * Dh + k0 + kk];
    }
#pragma unroll
    for (int i = 0; i < 12; ++i) {
      int e = i * 256 + tid;        // 32 k-rows x 96 cols
      int kk = e / 96, c = e - kk * 96;
      int g = c >> 5, dd = c & 31;
      Ws[kk][c] = WT[(size_t)(k0 + kk) * G3 + g * Dh + d0 + dd];
    }
    __syncthreads();
#pragma unroll
    for (int kk = 0; kk < 32; ++kk) {
      float h = Hs[kk][bb];
      float2 wr = *(const float2*)&Ws[kk][dg * 2];
      float2 wz = *(const float2*)&Ws[kk][32 + dg * 2];
      float2 wn = *(const float2*)&Ws[kk][64 + dg * 2];
      ar[0] = fmaf(h, wr.x, ar[0]); ar[1] = fmaf(h, wr.y, ar[1]);
      az[0] = fmaf(h, wz.x, az[0]); az[1] = fmaf(h, wz.y, az[1]);
      an[0] = fmaf(h, wn.x, an[0]); an[1] = fmaf(h, wn.y, an[1]);
    }
    __syncthreads();
  }

  const int b = b0 + bb;
  const int d = d0 + dg * 2;
  const unsigned short* gr = gi + ((size_t)b * seq + t) * G3;
  ushort2 ur = *(const ushort2*)&gr[d];
  ushort2 uz = *(const ushort2*)&gr[Dh + d];
  ushort2 un = *(const ushort2*)&gr[2 * Dh + d];
  float2 hp = *(const float2*)&h_in[(size_t)b * Dh + d];
  float2 br = *(const float2*)&bhh[d];
  float2 bz = *(const float2*)&bhh[Dh + d];
  float2 bn = *(const float2*)&bhh[2 * Dh + d];
  float gir[2] = {bf2f(ur.x), bf2f(ur.y)};
  float giz[2] = {bf2f(uz.x), bf2f(uz.y)};
  float gin[2] = {bf2f(un.x), bf2f(un.y)};
  float ghr[2] = {ar[0] + br.x, ar[1] + br.y};
  float ghz[2] = {az[0] + bz.x, az[1] + bz.y};
  float ghn[2] = {an[0] + bn.x, an[1] + bn.y};
  float hpv[2] = {hp.x, hp.y};
  float o[2];
#pragma unroll
  for (int j = 0; j < 2; ++j) {
    float r = 1.f / (1.f + expf(-(gir[j] + ghr[j])));
    float z = 1.f / (1.f + expf(-(giz[j] + ghz[j])));
    float n = tanhf(gin[j] + r * ghn[j]);
    o[j] = (1.f - z) * n + z * hpv[j];
  }
  float2 ov;
  ov.x = o[0];
  ov.y = o[1];
  *(float2*)&h_out[(size_t)b * Dh + d] = ov;
}

// in-place log_softmax over last dim (512); one wave per row
__global__ __launch_bounds__(256) void logsoftmax512(float* __restrict__ x) {
  const int row = blockIdx.x * 4 + (threadIdx.x >> 6);
  const int lane = threadIdx.x & 63;
  float* p = x + (size_t)row * NV + lane * 8;
  float4 v0 = *(const float4*)p;
  float4 v1 = *(const float4*)(p + 4);
  float m = fmaxf(fmaxf(fmaxf(v0.x, v0.y), fmaxf(v0.z, v0.w)),
                  fmaxf(fmaxf(v1.x, v1.y), fmaxf(v1.z, v1.w)));
#pragma unroll
  for (int o = 1; o < 64; o <<= 1) m = fmaxf(m, __shfl_xor(m, o, 64));
  float s = expf(v0.x - m) + expf(v0.y - m) + expf(v0.z - m) + expf(v0.w - m) +
            expf(v1.x - m) + expf(v1.y - m) + expf(v1.z - m) + expf(v1.w - m);
#pragma unroll
  for (int o = 1; o < 64; o <<= 1) s += __shfl_xor(s, o, 64);
  const float ls = m + logf(s);
  v0.x -= ls; v0.y -= ls; v0.z -= ls; v0.w -= ls;
  v1.x -= ls; v1.y -= ls; v1.z -= ls; v1.w -= ls;
  *(float4*)p = v0;
  *(float4*)(p + 4) = v1;
}

extern "C" void kernel_launch(void* const* d_in, const int* in_sizes, int n_in,
                              void* d_out, int out_size, void* d_ws, size_t ws_size,
                              hipStream_t stream) {
  (void)in_sizes; (void)n_in; (void)out_size; (void)ws_size;
  const int* src = (const int*)d_in[0];
  const int* trg = (const int*)d_in[1];
  // d_in[2], d_in[3] = masks: unused by the reference
  const float* enc_emb = (const float*)d_in[4];
  const float* enc_Wih = (const float*)d_in[5];
  const float* enc_Whh = (const float*)d_in[6];
  const float* enc_bih = (const float*)d_in[7];
  const float* enc_bhh = (const float*)d_in[8];
  const float* dec_emb = (const float*)d_in[9];
  const float* dec_Wih = (const float*)d_in[10];
  const float* dec_Whh = (const float*)d_in[11];
  const float* dec_bih = (const float*)d_in[12];
  const float* dec_bhh = (const float*)d_in[13];
  const float* out_W = (const float*)d_in[14];
  const float* out_b = (const float*)d_in[15];

  char* ws = (char*)d_ws;
  size_t off = 0;
  auto alloc = [&](size_t bytes) -> char* {
    char* p = ws + off;
    off += (bytes + 255) & ~(size_t)255;
    return p;
  };
  // total ~334 MiB
  unsigned short* gi = (unsigned short*)alloc((size_t)NB * SL * G3 * 2);  // bf16, reused enc->dec
  float* h_a = (float*)alloc((size_t)NB * Dh * 4);
  float* h_b = (float*)alloc((size_t)NB * Dh * 4);
  float* h_all = (float*)alloc((size_t)TL * NB * Dh * 4);
  float* WihT_e = (float*)alloc((size_t)Dh * G3 * 4);
  float* WhhT_e = (float*)alloc((size_t)Dh * G3 * 4);
  float* WihT_d = (float*)alloc((size_t)Dh * G3 * 4);
  float* WhhT_d = (float*)alloc((size_t)Dh * G3 * 4);
  float* outWT = (float*)alloc((size_t)Dh * NV * 4);

  {
    int n = G3 * Dh, blocks = (n + 255) / 256;
    transpose_f32<<<blocks, 256, 0, stream>>>(enc_Wih, WihT_e, G3, Dh);
    transpose_f32<<<blocks, 256, 0, stream>>>(enc_Whh, WhhT_e, G3, Dh);
    transpose_f32<<<blocks, 256, 0, stream>>>(dec_Wih, WihT_d, G3, Dh);
    transpose_f32<<<blocks, 256, 0, stream>>>(dec_Whh, WhhT_d, G3, Dh);
    int n2 = NV * Dh;
    transpose_f32<<<(n2 + 255) / 256, 256, 0, stream>>>(out_W, outWT, NV, Dh);
  }
  hipMemsetAsync(h_a, 0, (size_t)NB * Dh * 4, stream);  // h0 = 0

  // enc_gi = emb[src] @ WihT + bih   [B*S, 3D], bf16
  dim3 ggi(G3 / 128, (NB * SL) / 128);
  gemm128<0, false, true><<<ggi, 256, 0, stream>>>(enc_emb, src, WihT_e, enc_bih, gi, G3, Dh);

  dim3 gstep(Dh / 32, NB / 16);
  for (int t = 0; t < SL; ++t) {
    const float* hi = (t & 1) ? h_b : h_a;
    float* ho = (t & 1) ? h_a : h_b;
    gru_step<<<gstep, 256, 0, stream>>>(hi, ho, WhhT_e, gi, enc_bhh, t, SL);
  }
  // 256 steps (even) -> final encoder hidden is in h_a

  // dec_gi = relu(emb[trg]) @ WihT + bih, overwrites gi buffer
  gemm128<0, true, true><<<ggi, 256, 0, stream>>>(dec_emb, trg, WihT_d, dec_bih, gi, G3, Dh);

  for (int t = 0; t < TL; ++t) {
    const float* hi = (t == 0) ? h_a : (h_all + (size_t)(t - 1) * NB * Dh);
    float* ho = h_all + (size_t)t * NB * Dh;
    gru_step<<<gstep, 256, 0, stream>>>(hi, ho, WhhT_d, gi, dec_bhh, t, TL);
  }

  // logits[b*T+t, v] = h_all[t, b, :] @ outWT + out_b  -> d_out, then log_softmax
  dim3 glg(NV / 128, (NB * TL) / 128);
  gemm128<1, false, false><<<glg, 256, 0, stream>>>(h_all, nullptr, outWT, out_b, d_out, NV, Dh);

  logsoftmax512<<<(NB * TL) / 4, 256, 0, stream>>>((float*)d_out);
}

// Round 2
// 3787.423 us; speedup vs baseline: 3.9601x; 3.9601x over previous
//
#include <hip/hip_runtime.h>
#include <cstdint>
#include <cstddef>

namespace {
constexpr int Dh = 512;   // hidden / emb dim
constexpr int G3 = 1536;  // 3*Dh
constexpr int NB = 256;   // batch
constexpr int SL = 256;   // src len
constexpr int TL = 256;   // trg len
constexpr int NV = 512;   // vocab
}

typedef __attribute__((ext_vector_type(8))) short bf16x8;
typedef __attribute__((ext_vector_type(4))) float f32x4;

__device__ __forceinline__ unsigned short f2bf(float f) {
  unsigned int u = __float_as_uint(f);
  u = (u + 0x7FFFu + ((u >> 16) & 1u)) >> 16;  // RNE (finite, small values)
  return (unsigned short)u;
}
__device__ __forceinline__ float bf2f(unsigned short s) {
  return __uint_as_float(((unsigned int)s) << 16);
}

// f32 -> bf16 elementwise (optional relu), 4 elems/thread
__global__ __launch_bounds__(256) void cvt_bf16(const float* __restrict__ in,
                                                unsigned short* __restrict__ out,
                                                int n4, int relu) {
  int i = blockIdx.x * 256 + threadIdx.x;
  if (i >= n4) return;
  float4 v = ((const float4*)in)[i];
  if (relu) {
    v.x = fmaxf(v.x, 0.f); v.y = fmaxf(v.y, 0.f);
    v.z = fmaxf(v.z, 0.f); v.w = fmaxf(v.w, 0.f);
  }
  ushort4 o;
  o.x = f2bf(v.x); o.y = f2bf(v.y); o.z = f2bf(v.z); o.w = f2bf(v.w);
  ((ushort4*)out)[i] = o;
}

// C[M,N] = A(bf16) @ W(bf16 [N][K] native rows)^T-as-B + bias, K = 512.
// MFMA 16x16x32 bf16. 128x128 tile, BK=64, 256 threads = 4 waves (2x2 quadrants
// of 64x64). LDS k-chunked layout [kc][row][8] bf16 -> conflict-free b128 reads.
// AMODE 0: A row = Abase + idx[row]*K (embedding gather)
// AMODE 1: A row = Abase + ((row&255)*NB + (row>>8))*K (hb_all[t][b] for row=b*TL+t)
template <int AMODE, bool OUTBF16>
__global__ __launch_bounds__(256) void gemm_bf16(
    const unsigned short* __restrict__ Abase, const int* __restrict__ idx,
    const unsigned short* __restrict__ W, const float* __restrict__ bias,
    void* __restrict__ Cout, int N) {
  __shared__ unsigned short lds_a[8 * 128 * 8];  // 16 KB
  __shared__ unsigned short lds_b[8 * 128 * 8];  // 16 KB
  const int t = threadIdx.x;
  const int n0 = blockIdx.x * 128;
  const int m0 = blockIdx.y * 128;
  const int w = t >> 6, l = t & 63;
  const int mq = (w & 1) * 64, nq = (w >> 1) * 64;
  const int l15 = l & 15, lh = l >> 4;

  // staging: thread covers row sm, chunks sk..sk+3 (8 chunks of 8 k each = BK 64)
  const int sm = t & 127;
  const int sk = (t >> 7) * 4;
  const unsigned short* arow;
  if (AMODE == 0) {
    arow = Abase + (size_t)idx[m0 + sm] * Dh;
  } else {
    int row = m0 + sm;
    arow = Abase + ((size_t)(row & 255) * NB + (row >> 8)) * Dh;
  }
  const unsigned short* brow = W + (size_t)(n0 + sm) * Dh;

  f32x4 acc[4][4];
#pragma unroll
  for (int i = 0; i < 4; ++i)
#pragma unroll
    for (int j = 0; j < 4; ++j) acc[i][j] = (f32x4)0.f;

  for (int k0 = 0; k0 < Dh; k0 += 64) {
    __syncthreads();  // protect LDS against previous iteration's readers
#pragma unroll
    for (int i = 0; i < 4; ++i) {
      int kc = sk + i;
      *(uint4*)&lds_a[(kc * 128 + sm) * 8] = *(const uint4*)(arow + k0 + kc * 8);
      *(uint4*)&lds_b[(kc * 128 + sm) * 8] = *(const uint4*)(brow + k0 + kc * 8);
    }
    __syncthreads();
#pragma unroll
    for (int q = 0; q < 2; ++q) {
      bf16x8 af[4], bfr[4];
#pragma unroll
      for (int i = 0; i < 4; ++i)
        af[i] = *(const bf16x8*)&lds_a[((q * 4 + lh) * 128 + mq + i * 16 + l15) * 8];
#pragma unroll
      for (int j = 0; j < 4; ++j)
        bfr[j] = *(const bf16x8*)&lds_b[((q * 4 + lh) * 128 + nq + j * 16 + l15) * 8];
#pragma unroll
      for (int i = 0; i < 4; ++i)
#pragma unroll
        for (int j = 0; j < 4; ++j)
          acc[i][j] = __builtin_amdgcn_mfma_f32_16x16x32_bf16(af[i], bfr[j], acc[i][j], 0, 0, 0);
    }
  }

  // epilogue: D[(lh*4+r)][l15] per 16x16 tile
#pragma unroll
  for (int j = 0; j < 4; ++j) {
    const int col = n0 + nq + j * 16 + l15;
    const float bv = bias[col];
#pragma unroll
    for (int i = 0; i < 4; ++i) {
#pragma unroll
      for (int r = 0; r < 4; ++r) {
        const size_t row = (size_t)m0 + mq + i * 16 + lh * 4 + r;
        const float v = acc[i][j][r] + bv;
        if (OUTBF16)
          ((unsigned short*)Cout)[row * N + col] = f2bf(v);
        else
          ((float*)Cout)[row * N + col] = v;
      }
    }
  }
}

// One GRU step, MFMA. Grid (Dh/16=32, NB/32=8) = 256 WGs x 256 thr.
// WG owns 32 batch x 16 d (x3 gates = 48 c). Whh slice in LDS (48 KB,
// k-chunked). h read as bf16 a-frags straight from global (L2-resident).
// K=512 split across 4 waves (128 each), partials reduced through LDS.
__global__ __launch_bounds__(256) void gru_step(
    const float* __restrict__ h_in, const unsigned short* __restrict__ hb_in,
    float* __restrict__ h_out, unsigned short* __restrict__ hb_out,
    const unsigned short* __restrict__ W,   // Whh bf16 [1536][512] native
    const unsigned short* __restrict__ gi,  // bf16 [NB][seq][1536] (incl. bih)
    const float* __restrict__ bhh, int tstep, int seq) {
  __shared__ unsigned short lds_w[64 * 48 * 8];  // [kc][c][8] = 48 KB
  __shared__ float lds_red[4 * 6 * 256];         // [wave][mi*3+nj][row*16+col] = 24 KB
  const int t = threadIdx.x;
  const int d0 = blockIdx.x * 16;
  const int b0 = blockIdx.y * 32;
  const int w = t >> 6, l = t & 63;
  const int l15 = l & 15, lh = l >> 4;

  // stage Whh slice: 48 c-cols (3 gates x 16 d) x 512 k -> 3072 16B chunks
#pragma unroll
  for (int i = 0; i < 12; ++i) {
    int id = i * 256 + t;
    int kc = id & 63, c = id >> 6;
    int gate = c >> 4, dl = c & 15;
    const unsigned short* src = W + (size_t)(gate * Dh + d0 + dl) * Dh + kc * 8;
    *(uint4*)&lds_w[(kc * 48 + c) * 8] = *(const uint4*)src;
  }

  f32x4 acc[2][3];
#pragma unroll
  for (int mi = 0; mi < 2; ++mi)
#pragma unroll
    for (int nj = 0; nj < 3; ++nj) acc[mi][nj] = (f32x4)0.f;

  __syncthreads();

#pragma unroll
  for (int q = 0; q < 4; ++q) {
    const int kc32 = w * 4 + q;  // this wave's K quarter: k in [w*128, w*128+128)
    bf16x8 a[2], bfr[3];
#pragma unroll
    for (int mi = 0; mi < 2; ++mi)
      a[mi] = *(const bf16x8*)(hb_in + (size_t)(b0 + mi * 16 + l15) * Dh + kc32 * 32 + lh * 8);
#pragma unroll
    for (int nj = 0; nj < 3; ++nj)
      bfr[nj] = *(const bf16x8*)&lds_w[((kc32 * 4 + lh) * 48 + nj * 16 + l15) * 8];
#pragma unroll
    for (int mi = 0; mi < 2; ++mi)
#pragma unroll
      for (int nj = 0; nj < 3; ++nj)
        acc[mi][nj] = __builtin_amdgcn_mfma_f32_16x16x32_bf16(a[mi], bfr[nj], acc[mi][nj], 0, 0, 0);
  }

  // write per-wave partials
#pragma unroll
  for (int mi = 0; mi < 2; ++mi)
#pragma unroll
    for (int nj = 0; nj < 3; ++nj)
#pragma unroll
      for (int r = 0; r < 4; ++r)
        lds_red[(w * 6 + mi * 3 + nj) * 256 + (lh * 4 + r) * 16 + l15] = acc[mi][nj][r];
  __syncthreads();

  // reduce 4 waves + gates. thread -> (bl = t>>3, d pair dl = (t&7)*2)
  const int bl = t >> 3;
  const int dl = (t & 7) * 2;
  const int mi = bl >> 4, row = bl & 15;
  float gh[3][2];
#pragma unroll
  for (int g = 0; g < 3; ++g)
#pragma unroll
    for (int dd = 0; dd < 2; ++dd) {
      float s = 0.f;
#pragma unroll
      for (int ww = 0; ww < 4; ++ww)
        s += lds_red[(ww * 6 + mi * 3 + g) * 256 + row * 16 + dl + dd];
      gh[g][dd] = s;
    }

  const int b = b0 + bl;
  const int d = d0 + dl;
  const unsigned short* gr = gi + ((size_t)b * seq + tstep) * G3;
  ushort2 ur = *(const ushort2*)&gr[d];
  ushort2 uz = *(const ushort2*)&gr[Dh + d];
  ushort2 un = *(const ushort2*)&gr[2 * Dh + d];
  float2 hp = *(const float2*)&h_in[(size_t)b * Dh + d];
  float2 br = *(const float2*)&bhh[d];
  float2 bz = *(const float2*)&bhh[Dh + d];
  float2 bn = *(const float2*)&bhh[2 * Dh + d];
  const float gir[2] = {bf2f(ur.x), bf2f(ur.y)};
  const float giz[2] = {bf2f(uz.x), bf2f(uz.y)};
  const float gin[2] = {bf2f(un.x), bf2f(un.y)};
  const float brv[2] = {br.x, br.y}, bzv[2] = {bz.x, bz.y}, bnv[2] = {bn.x, bn.y};
  const float hpv[2] = {hp.x, hp.y};
  float o[2];
#pragma unroll
  for (int dd = 0; dd < 2; ++dd) {
    float rr = 1.f / (1.f + expf(-(gir[dd] + gh[0][dd] + brv[dd])));
    float zz = 1.f / (1.f + expf(-(giz[dd] + gh[1][dd] + bzv[dd])));
    float nn = tanhf(gin[dd] + rr * (gh[2][dd] + bnv[dd]));
    o[dd] = (1.f - zz) * nn + zz * hpv[dd];
  }
  float2 ov; ov.x = o[0]; ov.y = o[1];
  *(float2*)&h_out[(size_t)b * Dh + d] = ov;
  ushort2 ob; ob.x = f2bf(o[0]); ob.y = f2bf(o[1]);
  *(ushort2*)&hb_out[(size_t)b * Dh + d] = ob;
}

// in-place log_softmax over last dim (512); one wave per row
__global__ __launch_bounds__(256) void logsoftmax512(float* __restrict__ x) {
  const int row = blockIdx.x * 4 + (threadIdx.x >> 6);
  const int lane = threadIdx.x & 63;
  float* p = x + (size_t)row * NV + lane * 8;
  float4 v0 = *(const float4*)p;
  float4 v1 = *(const float4*)(p + 4);
  float m = fmaxf(fmaxf(fmaxf(v0.x, v0.y), fmaxf(v0.z, v0.w)),
                  fmaxf(fmaxf(v1.x, v1.y), fmaxf(v1.z, v1.w)));
#pragma unroll
  for (int o = 1; o < 64; o <<= 1) m = fmaxf(m, __shfl_xor(m, o, 64));
  float s = expf(v0.x - m) + expf(v0.y - m) + expf(v0.z - m) + expf(v0.w - m) +
            expf(v1.x - m) + expf(v1.y - m) + expf(v1.z - m) + expf(v1.w - m);
#pragma unroll
  for (int o = 1; o < 64; o <<= 1) s += __shfl_xor(s, o, 64);
  const float ls = m + logf(s);
  v0.x -= ls; v0.y -= ls; v0.z -= ls; v0.w -= ls;
  v1.x -= ls; v1.y -= ls; v1.z -= ls; v1.w -= ls;
  *(float4*)p = v0;
  *(float4*)(p + 4) = v1;
}

extern "C" void kernel_launch(void* const* d_in, const int* in_sizes, int n_in,
                              void* d_out, int out_size, void* d_ws, size_t ws_size,
                              hipStream_t stream) {
  (void)in_sizes; (void)n_in; (void)out_size; (void)ws_size;
  const int* src = (const int*)d_in[0];
  const int* trg = (const int*)d_in[1];
  const float* enc_emb = (const float*)d_in[4];
  const float* enc_Wih = (const float*)d_in[5];
  const float* enc_Whh = (const float*)d_in[6];
  const float* enc_bih = (const float*)d_in[7];
  const float* enc_bhh = (const float*)d_in[8];
  const float* dec_emb = (const float*)d_in[9];
  const float* dec_Wih = (const float*)d_in[10];
  const float* dec_Whh = (const float*)d_in[11];
  const float* dec_bih = (const float*)d_in[12];
  const float* dec_bhh = (const float*)d_in[13];
  const float* out_W = (const float*)d_in[14];
  const float* out_b = (const float*)d_in[15];

  char* ws = (char*)d_ws;
  size_t off = 0;
  auto alloc = [&](size_t bytes) -> char* {
    char* p = ws + off;
    off += (bytes + 255) & ~(size_t)255;
    return p;
  };
  typedef unsigned short u16;
  u16* gi = (u16*)alloc((size_t)NB * SL * G3 * 2);        // 201 MB (reused enc->dec)
  u16* hb_all = (u16*)alloc((size_t)TL * NB * Dh * 2);    // 67 MB decoder bf16 h
  float* h_a = (float*)alloc((size_t)NB * Dh * 4);
  float* h_b = (float*)alloc((size_t)NB * Dh * 4);
  u16* hb_a = (u16*)alloc((size_t)NB * Dh * 2);
  u16* hb_b = (u16*)alloc((size_t)NB * Dh * 2);
  u16* embB_e = (u16*)alloc((size_t)NV * Dh * 2);
  u16* embB_d = (u16*)alloc((size_t)NV * Dh * 2);         // relu pre-applied
  u16* WihB_e = (u16*)alloc((size_t)G3 * Dh * 2);
  u16* WhhB_e = (u16*)alloc((size_t)G3 * Dh * 2);
  u16* WihB_d = (u16*)alloc((size_t)G3 * Dh * 2);
  u16* WhhB_d = (u16*)alloc((size_t)G3 * Dh * 2);
  u16* outWB = (u16*)alloc((size_t)NV * Dh * 2);

  // ---- one-time conversions (weights stay in native [N][K] layout) ----
  cvt_bf16<<<(NV * Dh / 4 + 255) / 256, 256, 0, stream>>>(enc_emb, embB_e, NV * Dh / 4, 0);
  cvt_bf16<<<(NV * Dh / 4 + 255) / 256, 256, 0, stream>>>(dec_emb, embB_d, NV * Dh / 4, 1);
  cvt_bf16<<<(G3 * Dh / 4 + 255) / 256, 256, 0, stream>>>(enc_Wih, WihB_e, G3 * Dh / 4, 0);
  cvt_bf16<<<(G3 * Dh / 4 + 255) / 256, 256, 0, stream>>>(enc_Whh, WhhB_e, G3 * Dh / 4, 0);
  cvt_bf16<<<(G3 * Dh / 4 + 255) / 256, 256, 0, stream>>>(dec_Wih, WihB_d, G3 * Dh / 4, 0);
  cvt_bf16<<<(G3 * Dh / 4 + 255) / 256, 256, 0, stream>>>(dec_Whh, WhhB_d, G3 * Dh / 4, 0);
  cvt_bf16<<<(NV * Dh / 4 + 255) / 256, 256, 0, stream>>>(out_W, outWB, NV * Dh / 4, 0);
  hipMemsetAsync(h_a, 0, (size_t)NB * Dh * 4, stream);
  hipMemsetAsync(hb_a, 0, (size_t)NB * Dh * 2, stream);

  // ---- encoder gi = emb[src] @ Wih^T + bih (bf16 out) ----
  dim3 ggi(G3 / 128, NB * SL / 128);
  gemm_bf16<0, true><<<ggi, 256, 0, stream>>>(embB_e, src, WihB_e, enc_bih, gi, G3);

  // ---- encoder recurrence ----
  dim3 gstep(Dh / 16, NB / 32);
  for (int t = 0; t < SL; ++t) {
    const float* hi = (t & 1) ? h_b : h_a;
    float* ho = (t & 1) ? h_a : h_b;
    const u16* hbi = (t & 1) ? hb_b : hb_a;
    u16* hbo = (t & 1) ? hb_a : hb_b;
    gru_step<<<gstep, 256, 0, stream>>>(hi, hbi, ho, hbo, WhhB_e, gi, enc_bhh, t, SL);
  }
  // SL=256 even -> final encoder state in h_a / hb_a

  // ---- decoder gi = relu(emb[trg]) @ Wih^T + bih ----
  gemm_bf16<0, true><<<ggi, 256, 0, stream>>>(embB_d, trg, WihB_d, dec_bih, gi, G3);

  // ---- decoder recurrence, bf16 h archived to hb_all ----
  for (int t = 0; t < TL; ++t) {
    const float* hi = (t & 1) ? h_b : h_a;
    float* ho = (t & 1) ? h_a : h_b;
    const u16* hbi = (t == 0) ? hb_a : (hb_all + (size_t)(t - 1) * NB * Dh);
    u16* hbo = hb_all + (size_t)t * NB * Dh;
    gru_step<<<gstep, 256, 0, stream>>>(hi, hbi, ho, hbo, WhhB_d, gi, dec_bhh, t, TL);
  }

  // ---- logits = hb_all @ out_W^T + out_b -> d_out (fp32), then log_softmax ----
  dim3 glg(NV / 128, NB * TL / 128);
  gemm_bf16<1, false><<<glg, 256, 0, stream>>>(hb_all, nullptr, outWB, out_b, d_out, NV);
  logsoftmax512<<<NB * TL / 4, 256, 0, stream>>>((float*)d_out);
}